// Round 1
// baseline (4224.173 us; speedup 1.0000x reference)
//
#include <hip/hip_runtime.h>
#include <hip/hip_bf16.h>
#include <math.h>

#define T_TOK 8192
#define NE 1024
#define N_EXP 8
#define DFFN 2048
#define TW 16384        // total width = 8*2048
#define P_TOT 16384     // T_TOK * 2

// ---------------------------------------------------------------------------
// Kernel A: router — logits, softmax, top-2, normalized weights, loss partials
// ---------------------------------------------------------------------------
__global__ __launch_bounds__(256) void router_kernel(
    const float* __restrict__ x, const float* __restrict__ wr,
    int* __restrict__ sel_idx, float* __restrict__ sel_wt,
    float* __restrict__ z_part, float* __restrict__ p_part)
{
    __shared__ float wrs[N_EXP * NE];   // 32 KB
    __shared__ float red[256];
    int tid = threadIdx.x;
    for (int i = tid; i < N_EXP * NE; i += 256) wrs[i] = wr[i];
    __syncthreads();

    int t = blockIdx.x * 256 + tid;   // T_TOK == 32*256 exactly
    float lg[N_EXP];
#pragma unroll
    for (int e = 0; e < N_EXP; e++) lg[e] = 0.f;

    const float4* x4 = (const float4*)(x + (size_t)t * NE);
    for (int n4 = 0; n4 < NE / 4; n4++) {
        float4 xv = x4[n4];
#pragma unroll
        for (int e = 0; e < N_EXP; e++) {
            const float* w = &wrs[e * NE + n4 * 4];
            lg[e] += xv.x * w[0] + xv.y * w[1] + xv.z * w[2] + xv.w * w[3];
        }
    }

    // softmax over 8
    float m = lg[0];
#pragma unroll
    for (int e = 1; e < N_EXP; e++) m = fmaxf(m, lg[e]);
    float p[N_EXP], s = 0.f;
#pragma unroll
    for (int e = 0; e < N_EXP; e++) { p[e] = expf(lg[e] - m); s += p[e]; }
    float inv = 1.f / s;
#pragma unroll
    for (int e = 0; e < N_EXP; e++) p[e] *= inv;
    float lse = m + logf(s);

    // top-2 (ties -> lower index, matching lax.top_k)
    int e0 = 0;
#pragma unroll
    for (int e = 1; e < N_EXP; e++) if (p[e] > p[e0]) e0 = e;
    int e1 = (e0 == 0) ? 1 : 0;
#pragma unroll
    for (int e = 0; e < N_EXP; e++) if (e != e0 && p[e] > p[e1]) e1 = e;

    float wn = 1.f / (p[e0] + p[e1]);
    sel_idx[t * 2 + 0] = e0;
    sel_idx[t * 2 + 1] = e1;
    sel_wt[t * 2 + 0] = p[e0] * wn;
    sel_wt[t * 2 + 1] = p[e1] * wn;

    // block reductions (deterministic tree)
    red[tid] = lse * lse;
    __syncthreads();
    for (int st = 128; st > 0; st >>= 1) {
        if (tid < st) red[tid] += red[tid + st];
        __syncthreads();
    }
    if (tid == 0) z_part[blockIdx.x] = red[0];
#pragma unroll
    for (int e = 0; e < N_EXP; e++) {
        __syncthreads();
        red[tid] = p[e];
        __syncthreads();
        for (int st = 128; st > 0; st >>= 1) {
            if (tid < st) red[tid] += red[tid + st];
            __syncthreads();
        }
        if (tid == 0) p_part[blockIdx.x * N_EXP + e] = red[0];
    }
}

// ---------------------------------------------------------------------------
// Kernel B: counts (by scan, no atomics), offsets, cursors, aux-loss outputs
// ---------------------------------------------------------------------------
__global__ __launch_bounds__(256) void finalize_router(
    const int* __restrict__ sel_idx,
    const float* __restrict__ z_part, const float* __restrict__ p_part,
    int* __restrict__ cnt, int* __restrict__ off, int* __restrict__ cursor,
    float* __restrict__ out)
{
    __shared__ int redc[256];
    __shared__ int cnts[N_EXP];
    int tid = threadIdx.x;
    int c[N_EXP];
#pragma unroll
    for (int e = 0; e < N_EXP; e++) c[e] = 0;
    for (int i = tid; i < P_TOT; i += 256) c[sel_idx[i]]++;
#pragma unroll
    for (int e = 0; e < N_EXP; e++) {
        redc[tid] = c[e];
        __syncthreads();
        for (int st = 128; st > 0; st >>= 1) {
            if (tid < st) redc[tid] += redc[tid + st];
            __syncthreads();
        }
        if (tid == 0) cnts[e] = redc[0];
        __syncthreads();
    }
    if (tid == 0) {
        int o = 0;
        for (int e = 0; e < N_EXP; e++) {
            cnt[e] = cnts[e];
            off[e] = o;
            o += cnts[e];
            cursor[e] = 0;
        }
        off[N_EXP] = o;
        float zs = 0.f;
        for (int b = 0; b < 32; b++) zs += z_part[b];
        float lb = 0.f;
        float* tail = out + (size_t)T_TOK * NE;
        for (int e = 0; e < N_EXP; e++) {
            float ps = 0.f;
            for (int b = 0; b < 32; b++) ps += p_part[b * N_EXP + e];
            float fi = (float)cnts[e] / (float)P_TOT;
            float pi = ps / (float)T_TOK;
            lb += fi * pi;
            tail[2 + e] = fi;
        }
        tail[0] = zs / (float)T_TOK;       // router_z_loss
        tail[1] = 8.f * lb;                // load_balance_loss
    }
}

// ---------------------------------------------------------------------------
// Kernel C: scatter (token,slot) pairs into per-expert lists
// ---------------------------------------------------------------------------
__global__ __launch_bounds__(256) void scatter_kernel(
    const int* __restrict__ sel_idx, const int* __restrict__ off,
    int* __restrict__ cursor, int* __restrict__ token_list)
{
    int i = blockIdx.x * 256 + threadIdx.x;
    if (i < P_TOT) {
        int e = sel_idx[i];
        int pos = atomicAdd(&cursor[e], 1);
        token_list[off[e] + pos] = i;   // encodes token = i>>1, slot = i&1
    }
}

// ---------------------------------------------------------------------------
// Kernel D: grouped GEMM1  h[p, :] = gelu(x[tok(p), :] @ W1_e)   (h in bf16)
// ---------------------------------------------------------------------------
__global__ __launch_bounds__(256) void gemm1_kernel(
    const float* __restrict__ x, const float* __restrict__ w1,
    const int* __restrict__ token_list,
    const int* __restrict__ cnt, const int* __restrict__ off,
    __hip_bfloat16* __restrict__ h)
{
    int e = blockIdx.z;
    int cnt_e = cnt[e];
    int rowbase = blockIdx.x * 64;
    if (rowbase >= cnt_e) return;
    int off_e = off[e];
    int colbase = blockIdx.y * 64;
    int rows_e = cnt_e - rowbase;   // valid rows this tile (may exceed 64)

    __shared__ float Xs[64][33];
    __shared__ float Ws[32][65];
    __shared__ int rows[64];
    int tid = threadIdx.x;
    if (tid < 64)
        rows[tid] = (tid < rows_e) ? (token_list[off_e + rowbase + tid] >> 1) : -1;
    __syncthreads();

    float acc[4][4];
#pragma unroll
    for (int u = 0; u < 4; u++)
#pragma unroll
        for (int v = 0; v < 4; v++) acc[u][v] = 0.f;

    int tx = tid & 15, ty = tid >> 4;
    for (int kb = 0; kb < NE; kb += 32) {
#pragma unroll
        for (int l = 0; l < 8; l++) {
            int idx = tid + l * 256;
            int r = idx >> 5, k = idx & 31;
            int tok = rows[r];
            Xs[r][k] = (tok >= 0) ? x[(size_t)tok * NE + kb + k] : 0.f;
        }
#pragma unroll
        for (int l = 0; l < 8; l++) {
            int idx = tid + l * 256;
            int kk = idx >> 6, j = idx & 63;
            Ws[kk][j] = w1[(size_t)(kb + kk) * TW + e * DFFN + colbase + j];
        }
        __syncthreads();
#pragma unroll
        for (int k = 0; k < 32; k++) {
            float a[4], b[4];
#pragma unroll
            for (int u = 0; u < 4; u++) a[u] = Xs[ty * 4 + u][k];
#pragma unroll
            for (int v = 0; v < 4; v++) b[v] = Ws[k][tx * 4 + v];
#pragma unroll
            for (int u = 0; u < 4; u++)
#pragma unroll
                for (int v = 0; v < 4; v++) acc[u][v] += a[u] * b[v];
        }
        __syncthreads();
    }

#pragma unroll
    for (int u = 0; u < 4; u++) {
        int r = ty * 4 + u;
        if (r < rows_e) {
            size_t p = (size_t)off_e + rowbase + r;
#pragma unroll
            for (int v = 0; v < 4; v++) {
                float hv = acc[u][v];
                float g = 0.5f * hv * (1.f + erff(hv * 0.70710678118f)); // exact gelu
                h[p * DFFN + colbase + tx * 4 + v] = __float2bfloat16(g);
            }
        }
    }
}

// ---------------------------------------------------------------------------
// Kernel E: grouped GEMM2  out[tok] += w * (h[p, :] @ W2_e)
// ---------------------------------------------------------------------------
__global__ __launch_bounds__(256) void gemm2_kernel(
    const __hip_bfloat16* __restrict__ h, const float* __restrict__ w2,
    const int* __restrict__ token_list, const float* __restrict__ sel_wt,
    const int* __restrict__ cnt, const int* __restrict__ off,
    float* __restrict__ out)
{
    int e = blockIdx.z;
    int cnt_e = cnt[e];
    int rowbase = blockIdx.x * 64;
    if (rowbase >= cnt_e) return;
    int off_e = off[e];
    int colbase = blockIdx.y * 64;
    int rows_e = cnt_e - rowbase;

    __shared__ float Hs[64][33];
    __shared__ float Ws[32][65];
    __shared__ int li[64];
    int tid = threadIdx.x;
    if (tid < 64)
        li[tid] = (tid < rows_e) ? token_list[off_e + rowbase + tid] : -1;
    __syncthreads();

    float acc[4][4];
#pragma unroll
    for (int u = 0; u < 4; u++)
#pragma unroll
        for (int v = 0; v < 4; v++) acc[u][v] = 0.f;

    int tx = tid & 15, ty = tid >> 4;
    for (int kb = 0; kb < DFFN; kb += 32) {
#pragma unroll
        for (int l = 0; l < 8; l++) {
            int idx = tid + l * 256;
            int r = idx >> 5, k = idx & 31;
            Hs[r][k] = (r < rows_e)
                ? __bfloat162float(h[(size_t)(off_e + rowbase + r) * DFFN + kb + k])
                : 0.f;
        }
#pragma unroll
        for (int l = 0; l < 8; l++) {
            int idx = tid + l * 256;
            int kk = idx >> 6, j = idx & 63;
            Ws[kk][j] = w2[(size_t)(e * DFFN + kb + kk) * NE + colbase + j];
        }
        __syncthreads();
#pragma unroll
        for (int k = 0; k < 32; k++) {
            float a[4], b[4];
#pragma unroll
            for (int u = 0; u < 4; u++) a[u] = Hs[ty * 4 + u][k];
#pragma unroll
            for (int v = 0; v < 4; v++) b[v] = Ws[k][tx * 4 + v];
#pragma unroll
            for (int u = 0; u < 4; u++)
#pragma unroll
                for (int v = 0; v < 4; v++) acc[u][v] += a[u] * b[v];
        }
        __syncthreads();
    }

#pragma unroll
    for (int u = 0; u < 4; u++) {
        int r = ty * 4 + u;
        if (r < rows_e) {
            int ent = li[r];
            int t = ent >> 1;
            float w = sel_wt[ent];
#pragma unroll
            for (int v = 0; v < 4; v++)
                atomicAdd(&out[(size_t)t * NE + colbase + tx * 4 + v], w * acc[u][v]);
        }
    }
}

// ---------------------------------------------------------------------------
extern "C" void kernel_launch(void* const* d_in, const int* in_sizes, int n_in,
                              void* d_out, int out_size, void* d_ws, size_t ws_size,
                              hipStream_t stream)
{
    const float* x  = (const float*)d_in[0];
    const float* wr = (const float*)d_in[1];
    const float* w1 = (const float*)d_in[2];
    const float* w2 = (const float*)d_in[3];
    float* out = (float*)d_out;

    // workspace layout (needs ~67.3 MB)
    char* ws = (char*)d_ws;
    __hip_bfloat16* h = (__hip_bfloat16*)ws;
    size_t o = (size_t)P_TOT * DFFN * sizeof(__hip_bfloat16);   // 67108864
    int*   sel_idx    = (int*)(ws + o);   o += P_TOT * 4;
    float* sel_wt     = (float*)(ws + o); o += P_TOT * 4;
    int*   token_list = (int*)(ws + o);   o += P_TOT * 4;
    int*   cnt        = (int*)(ws + o);   o += 64;   // 8 used
    int*   off        = (int*)(ws + o);   o += 64;   // 9 used
    int*   cursor     = (int*)(ws + o);   o += 64;   // 8 used
    float* z_part     = (float*)(ws + o); o += 32 * 4;
    float* p_part     = (float*)(ws + o); o += 32 * N_EXP * 4;

    // zero the output (atomic accumulation target); tail is overwritten later
    hipMemsetAsync(d_out, 0, (size_t)out_size * sizeof(float), stream);

    router_kernel<<<32, 256, 0, stream>>>(x, wr, sel_idx, sel_wt, z_part, p_part);
    finalize_router<<<1, 256, 0, stream>>>(sel_idx, z_part, p_part, cnt, off, cursor, out);
    scatter_kernel<<<64, 256, 0, stream>>>(sel_idx, off, cursor, token_list);
    gemm1_kernel<<<dim3(128, 32, 8), 256, 0, stream>>>(x, w1, token_list, cnt, off, h);
    gemm2_kernel<<<dim3(128, 16, 8), 256, 0, stream>>>(h, w2, token_list, sel_wt, cnt, off, out);
}

// Round 2
// 605.839 us; speedup vs baseline: 6.9724x; 6.9724x over previous
//
#include <hip/hip_runtime.h>
#include <hip/hip_bf16.h>
#include <math.h>

#define T_TOK 8192
#define NE 1024
#define N_EXP 8
#define DFFN 2048
#define TW 16384        // total width = 8*2048
#define P_TOT 16384     // T_TOK * 2

typedef __attribute__((ext_vector_type(8))) short bf16x8;
typedef __attribute__((ext_vector_type(4))) float f32x4;

#define GLOAD_LDS16(g, l) __builtin_amdgcn_global_load_lds( \
    (const __attribute__((address_space(1))) void*)(g), \
    (__attribute__((address_space(3))) void*)(l), 16, 0, 0)

static __device__ __forceinline__ unsigned short f2bf(float f) {
    __hip_bfloat16 b = __float2bfloat16(f);
    return *(unsigned short*)&b;
}

// ---------------------------------------------------------------------------
// Kernel A: router — logits, softmax, top-2, normalized weights, loss partials
// (f32 throughout: bf16 logits would flip near-tie top-k selections)
// ---------------------------------------------------------------------------
__global__ __launch_bounds__(256) void router_kernel(
    const float* __restrict__ x, const float* __restrict__ wr,
    int* __restrict__ sel_idx, float* __restrict__ sel_wt,
    float* __restrict__ z_part, float* __restrict__ p_part)
{
    __shared__ float wrs[N_EXP * NE];   // 32 KB
    __shared__ float red[256];
    int tid = threadIdx.x;
    for (int i = tid; i < N_EXP * NE; i += 256) wrs[i] = wr[i];
    __syncthreads();

    int t = blockIdx.x * 256 + tid;   // T_TOK == 32*256 exactly
    float lg[N_EXP];
#pragma unroll
    for (int e = 0; e < N_EXP; e++) lg[e] = 0.f;

    const float4* x4 = (const float4*)(x + (size_t)t * NE);
    for (int n4 = 0; n4 < NE / 4; n4++) {
        float4 xv = x4[n4];
#pragma unroll
        for (int e = 0; e < N_EXP; e++) {
            const float* w = &wrs[e * NE + n4 * 4];
            lg[e] += xv.x * w[0] + xv.y * w[1] + xv.z * w[2] + xv.w * w[3];
        }
    }

    float m = lg[0];
#pragma unroll
    for (int e = 1; e < N_EXP; e++) m = fmaxf(m, lg[e]);
    float p[N_EXP], s = 0.f;
#pragma unroll
    for (int e = 0; e < N_EXP; e++) { p[e] = expf(lg[e] - m); s += p[e]; }
    float inv = 1.f / s;
#pragma unroll
    for (int e = 0; e < N_EXP; e++) p[e] *= inv;
    float lse = m + logf(s);

    int e0 = 0;
#pragma unroll
    for (int e = 1; e < N_EXP; e++) if (p[e] > p[e0]) e0 = e;
    int e1 = (e0 == 0) ? 1 : 0;
#pragma unroll
    for (int e = 0; e < N_EXP; e++) if (e != e0 && p[e] > p[e1]) e1 = e;

    float wn = 1.f / (p[e0] + p[e1]);
    sel_idx[t * 2 + 0] = e0;
    sel_idx[t * 2 + 1] = e1;
    sel_wt[t * 2 + 0] = p[e0] * wn;
    sel_wt[t * 2 + 1] = p[e1] * wn;

    red[tid] = lse * lse;
    __syncthreads();
    for (int st = 128; st > 0; st >>= 1) {
        if (tid < st) red[tid] += red[tid + st];
        __syncthreads();
    }
    if (tid == 0) z_part[blockIdx.x] = red[0];
#pragma unroll
    for (int e = 0; e < N_EXP; e++) {
        __syncthreads();
        red[tid] = p[e];
        __syncthreads();
        for (int st = 128; st > 0; st >>= 1) {
            if (tid < st) red[tid] += red[tid + st];
            __syncthreads();
        }
        if (tid == 0) p_part[blockIdx.x * N_EXP + e] = red[0];
    }
}

// ---------------------------------------------------------------------------
// Kernel B: counts (by scan), offsets, cursors, aux-loss outputs
// ---------------------------------------------------------------------------
__global__ __launch_bounds__(256) void finalize_router(
    const int* __restrict__ sel_idx,
    const float* __restrict__ z_part, const float* __restrict__ p_part,
    int* __restrict__ cnt, int* __restrict__ off, int* __restrict__ cursor,
    float* __restrict__ out)
{
    __shared__ int redc[256];
    __shared__ int cnts[N_EXP];
    int tid = threadIdx.x;
    int c[N_EXP];
#pragma unroll
    for (int e = 0; e < N_EXP; e++) c[e] = 0;
    for (int i = tid; i < P_TOT; i += 256) c[sel_idx[i]]++;
#pragma unroll
    for (int e = 0; e < N_EXP; e++) {
        redc[tid] = c[e];
        __syncthreads();
        for (int st = 128; st > 0; st >>= 1) {
            if (tid < st) redc[tid] += redc[tid + st];
            __syncthreads();
        }
        if (tid == 0) cnts[e] = redc[0];
        __syncthreads();
    }
    if (tid == 0) {
        int o = 0;
        for (int e = 0; e < N_EXP; e++) {
            cnt[e] = cnts[e];
            off[e] = o;
            o += cnts[e];
            cursor[e] = 0;
        }
        off[N_EXP] = o;
        float zs = 0.f;
        for (int b = 0; b < 32; b++) zs += z_part[b];
        float lb = 0.f;
        float* tail = out + (size_t)T_TOK * NE;
        for (int e = 0; e < N_EXP; e++) {
            float ps = 0.f;
            for (int b = 0; b < 32; b++) ps += p_part[b * N_EXP + e];
            float fi = (float)cnts[e] / (float)P_TOT;
            float pi = ps / (float)T_TOK;
            lb += fi * pi;
            tail[2 + e] = fi;
        }
        tail[0] = zs / (float)T_TOK;       // router_z_loss
        tail[1] = 8.f * lb;                // load_balance_loss
    }
}

// ---------------------------------------------------------------------------
// Kernel C: scatter (token,slot) pairs into per-expert lists
// ---------------------------------------------------------------------------
__global__ __launch_bounds__(256) void scatter_kernel(
    const int* __restrict__ sel_idx, const int* __restrict__ off,
    int* __restrict__ cursor, int* __restrict__ token_list)
{
    int i = blockIdx.x * 256 + threadIdx.x;
    if (i < P_TOT) {
        int e = sel_idx[i];
        int pos = atomicAdd(&cursor[e], 1);
        token_list[off[e] + pos] = i;   // token = i>>1, slot = i&1
    }
}

// ---------------------------------------------------------------------------
// Kernel P1: x f32 -> bf16 (same layout)
// ---------------------------------------------------------------------------
__global__ __launch_bounds__(256) void cvt_x_kernel(
    const float* __restrict__ x, unsigned short* __restrict__ xb)
{
    int i = blockIdx.x * 256 + threadIdx.x;     // one float4 per thread
    float4 v = ((const float4*)x)[i];
    ushort4 o;
    o.x = f2bf(v.x); o.y = f2bf(v.y); o.z = f2bf(v.z); o.w = f2bf(v.w);
    ((ushort4*)xb)[i] = o;
}

// ---------------------------------------------------------------------------
// Kernel P2: transpose + convert: src [R][C] f32 -> dst [C][R] bf16
// ---------------------------------------------------------------------------
__global__ __launch_bounds__(256) void transpose_bf16_kernel(
    const float* __restrict__ src, unsigned short* __restrict__ dst,
    int R, int C)
{
    __shared__ float tile[64][65];
    int rb = blockIdx.y * 64, cb = blockIdx.x * 64;
    int tid = threadIdx.x;
#pragma unroll
    for (int p = 0; p < 16; p++) {
        int idx = p * 256 + tid;
        int r = idx >> 6, c = idx & 63;
        tile[r][c] = src[(size_t)(rb + r) * C + cb + c];
    }
    __syncthreads();
#pragma unroll
    for (int p = 0; p < 16; p++) {
        int idx = p * 256 + tid;
        int c = idx >> 6, r = idx & 63;
        dst[(size_t)(cb + c) * R + rb + r] = f2bf(tile[r][c]);
    }
}

// ---------------------------------------------------------------------------
// Kernel D: grouped MFMA GEMM1: h[p,:] = selw[p] * gelu(xb[tok(p),:] @ W1_e)
// 128x128 tile, BK=32, 4 waves (2x2), mfma_f32_16x16x32_bf16, m97 structure.
// A gathered via per-lane global_load_lds source addresses.
// ---------------------------------------------------------------------------
__global__ __launch_bounds__(256) void gemm1_mfma(
    const __hip_bfloat16* __restrict__ xb, const __hip_bfloat16* __restrict__ w1t,
    const int* __restrict__ token_list, const float* __restrict__ sel_wt,
    const int* __restrict__ cnt, const int* __restrict__ off,
    __hip_bfloat16* __restrict__ h)
{
    int e = blockIdx.z;
    int cnt_e = cnt[e];
    int rowbase = blockIdx.x * 128;
    if (rowbase >= cnt_e) return;
    int off_e = off[e];
    int colbase = blockIdx.y * 128;
    int rows_e = cnt_e - rowbase;

    __shared__ __hip_bfloat16 As[128 * 32];   // [row][k], 64B/row, 8KB
    __shared__ __hip_bfloat16 Bs[128 * 32];   // [n][k],  64B/row, 8KB
    __shared__ int   toks[128];
    __shared__ float wrow[128];

    int tid = threadIdx.x;
    if (tid < 128) {
        int r = tid;
        int ent = token_list[off_e + rowbase + ((r < rows_e) ? r : 0)];
        toks[r] = ent >> 1;
        wrow[r] = sel_wt[ent];
    }
    __syncthreads();

    int wid = tid >> 6, lane = tid & 63;
    int wr = wid >> 1, wc = wid & 1;

    // staging geometry: chunk c = wid*2+j covers rows [c*16, c*16+16), 1KB each
    int row0 = wid * 32 + (lane >> 2);        // chunk j=0 row
    int kcol = (lane & 3) * 8;                // k element offset (16B)
    const __hip_bfloat16* asrc0 = xb + (size_t)toks[row0] * NE + kcol;
    const __hip_bfloat16* asrc1 = xb + (size_t)toks[row0 + 16] * NE + kcol;
    const __hip_bfloat16* bsrc0 = w1t + (size_t)(e * DFFN + colbase + row0) * NE + kcol;
    const __hip_bfloat16* bsrc1 = bsrc0 + (size_t)16 * NE;
    __hip_bfloat16* aldst0 = As + (wid * 2 + 0) * 512;
    __hip_bfloat16* aldst1 = As + (wid * 2 + 1) * 512;
    __hip_bfloat16* bldst0 = Bs + (wid * 2 + 0) * 512;
    __hip_bfloat16* bldst1 = Bs + (wid * 2 + 1) * 512;

    f32x4 acc[4][4] = {};
    int kq = lane >> 4;        // 0..3
    int rr = lane & 15;

    for (int kb = 0; kb < NE; kb += 32) {
        GLOAD_LDS16(asrc0 + kb, aldst0);
        GLOAD_LDS16(asrc1 + kb, aldst1);
        GLOAD_LDS16(bsrc0 + kb, bldst0);
        GLOAD_LDS16(bsrc1 + kb, bldst1);
        __syncthreads();

        bf16x8 af[4], bfr[4];
#pragma unroll
        for (int m = 0; m < 4; m++)
            af[m] = *(const bf16x8*)(As + (wr * 64 + m * 16 + rr) * 32 + kq * 8);
#pragma unroll
        for (int n = 0; n < 4; n++)
            bfr[n] = *(const bf16x8*)(Bs + (wc * 64 + n * 16 + rr) * 32 + kq * 8);
#pragma unroll
        for (int m = 0; m < 4; m++)
#pragma unroll
            for (int n = 0; n < 4; n++)
                acc[m][n] = __builtin_amdgcn_mfma_f32_16x16x32_bf16(
                    af[m], bfr[n], acc[m][n], 0, 0, 0);
        __syncthreads();
    }

    int colg = colbase + wc * 64;
#pragma unroll
    for (int m = 0; m < 4; m++) {
        int rb4 = wr * 64 + m * 16 + (lane >> 4) * 4;
#pragma unroll
        for (int j = 0; j < 4; j++) {
            int r = rb4 + j;
            if (r < rows_e) {
                size_t p = (size_t)off_e + rowbase + r;
                float wgt = wrow[r];
#pragma unroll
                for (int n = 0; n < 4; n++) {
                    float v = acc[m][n][j];
                    float g = 0.5f * v * (1.f + erff(v * 0.70710678118f));
                    h[p * DFFN + colg + n * 16 + (lane & 15)] = __float2bfloat16(wgt * g);
                }
            }
        }
    }
}

// ---------------------------------------------------------------------------
// Kernel E: grouped MFMA GEMM2: out[tok(p),:] += h[p,:] @ W2_e  (atomic f32)
// ---------------------------------------------------------------------------
__global__ __launch_bounds__(256) void gemm2_mfma(
    const __hip_bfloat16* __restrict__ h, const __hip_bfloat16* __restrict__ w2t,
    const int* __restrict__ token_list,
    const int* __restrict__ cnt, const int* __restrict__ off,
    float* __restrict__ out)
{
    int e = blockIdx.z;
    int cnt_e = cnt[e];
    int rowbase = blockIdx.x * 128;
    if (rowbase >= cnt_e) return;
    int off_e = off[e];
    int colbase = blockIdx.y * 128;
    int rows_e = cnt_e - rowbase;

    __shared__ __hip_bfloat16 As[128 * 32];
    __shared__ __hip_bfloat16 Bs[128 * 32];
    __shared__ int trow[128];

    int tid = threadIdx.x;
    if (tid < 128) {
        int r = tid;
        int ent = token_list[off_e + rowbase + ((r < rows_e) ? r : 0)];
        trow[r] = ent >> 1;
    }
    __syncthreads();

    int wid = tid >> 6, lane = tid & 63;
    int wr = wid >> 1, wc = wid & 1;

    int row0 = wid * 32 + (lane >> 2);
    int kcol = (lane & 3) * 8;
    int ar0 = rowbase + ((row0 < rows_e) ? row0 : 0);
    int ar1 = rowbase + ((row0 + 16 < rows_e) ? row0 + 16 : 0);
    const __hip_bfloat16* asrc0 = h + ((size_t)off_e + ar0) * DFFN + kcol;
    const __hip_bfloat16* asrc1 = h + ((size_t)off_e + ar1) * DFFN + kcol;
    const __hip_bfloat16* bsrc0 = w2t + (size_t)(colbase + row0) * TW + e * DFFN + kcol;
    const __hip_bfloat16* bsrc1 = bsrc0 + (size_t)16 * TW;
    __hip_bfloat16* aldst0 = As + (wid * 2 + 0) * 512;
    __hip_bfloat16* aldst1 = As + (wid * 2 + 1) * 512;
    __hip_bfloat16* bldst0 = Bs + (wid * 2 + 0) * 512;
    __hip_bfloat16* bldst1 = Bs + (wid * 2 + 1) * 512;

    f32x4 acc[4][4] = {};
    int kq = lane >> 4;
    int rr = lane & 15;

    for (int kb = 0; kb < DFFN; kb += 32) {
        GLOAD_LDS16(asrc0 + kb, aldst0);
        GLOAD_LDS16(asrc1 + kb, aldst1);
        GLOAD_LDS16(bsrc0 + kb, bldst0);
        GLOAD_LDS16(bsrc1 + kb, bldst1);
        __syncthreads();

        bf16x8 af[4], bfr[4];
#pragma unroll
        for (int m = 0; m < 4; m++)
            af[m] = *(const bf16x8*)(As + (wr * 64 + m * 16 + rr) * 32 + kq * 8);
#pragma unroll
        for (int n = 0; n < 4; n++)
            bfr[n] = *(const bf16x8*)(Bs + (wc * 64 + n * 16 + rr) * 32 + kq * 8);
#pragma unroll
        for (int m = 0; m < 4; m++)
#pragma unroll
            for (int n = 0; n < 4; n++)
                acc[m][n] = __builtin_amdgcn_mfma_f32_16x16x32_bf16(
                    af[m], bfr[n], acc[m][n], 0, 0, 0);
        __syncthreads();
    }

    int colg = colbase + wc * 64;
#pragma unroll
    for (int m = 0; m < 4; m++) {
        int rb4 = wr * 64 + m * 16 + (lane >> 4) * 4;
#pragma unroll
        for (int j = 0; j < 4; j++) {
            int r = rb4 + j;
            if (r < rows_e) {
                int t = trow[r];
#pragma unroll
                for (int n = 0; n < 4; n++)
                    atomicAdd(&out[(size_t)t * NE + colg + n * 16 + (lane & 15)],
                              acc[m][n][j]);
            }
        }
    }
}

// ---------------------------------------------------------------------------
extern "C" void kernel_launch(void* const* d_in, const int* in_sizes, int n_in,
                              void* d_out, int out_size, void* d_ws, size_t ws_size,
                              hipStream_t stream)
{
    const float* x  = (const float*)d_in[0];
    const float* wr = (const float*)d_in[1];
    const float* w1 = (const float*)d_in[2];
    const float* w2 = (const float*)d_in[3];
    float* out = (float*)d_out;

    // workspace layout (~151.3 MB)
    char* ws = (char*)d_ws;
    size_t o = 0;
    __hip_bfloat16* h   = (__hip_bfloat16*)(ws + o); o += (size_t)P_TOT * DFFN * 2;  // 67.1MB
    __hip_bfloat16* xb  = (__hip_bfloat16*)(ws + o); o += (size_t)T_TOK * NE * 2;    // 16.8MB
    __hip_bfloat16* w1t = (__hip_bfloat16*)(ws + o); o += (size_t)NE * TW * 2;       // 33.6MB  [TW][NE]
    __hip_bfloat16* w2t = (__hip_bfloat16*)(ws + o); o += (size_t)TW * NE * 2;       // 33.6MB  [NE][TW]
    int*   sel_idx    = (int*)(ws + o);   o += P_TOT * 4;
    float* sel_wt     = (float*)(ws + o); o += P_TOT * 4;
    int*   token_list = (int*)(ws + o);   o += P_TOT * 4;
    int*   cnt        = (int*)(ws + o);   o += 64;
    int*   off        = (int*)(ws + o);   o += 64;
    int*   cursor     = (int*)(ws + o);   o += 64;
    float* z_part     = (float*)(ws + o); o += 32 * 4;
    float* p_part     = (float*)(ws + o); o += 32 * N_EXP * 4;

    hipMemsetAsync(d_out, 0, (size_t)out_size * sizeof(float), stream);

    cvt_x_kernel<<<T_TOK * NE / 4 / 256, 256, 0, stream>>>(x, (unsigned short*)xb);
    transpose_bf16_kernel<<<dim3(TW / 64, NE / 64), 256, 0, stream>>>(
        w1, (unsigned short*)w1t, NE, TW);     // w1 [NE][TW] -> w1t [TW][NE]
    transpose_bf16_kernel<<<dim3(NE / 64, TW / 64), 256, 0, stream>>>(
        w2, (unsigned short*)w2t, TW, NE);     // w2 [TW][NE] -> w2t [NE][TW]

    router_kernel<<<32, 256, 0, stream>>>(x, wr, sel_idx, sel_wt, z_part, p_part);
    finalize_router<<<1, 256, 0, stream>>>(sel_idx, z_part, p_part, cnt, off, cursor, out);
    scatter_kernel<<<64, 256, 0, stream>>>(sel_idx, off, cursor, token_list);

    gemm1_mfma<<<dim3(128, DFFN / 128, N_EXP), 256, 0, stream>>>(
        xb, w1t, token_list, sel_wt, cnt, off, h);
    gemm2_mfma<<<dim3(128, NE / 128, N_EXP), 256, 0, stream>>>(
        h, w2t, token_list, cnt, off, out);
}

// Round 3
// 542.255 us; speedup vs baseline: 7.7900x; 1.1173x over previous
//
#include <hip/hip_runtime.h>
#include <hip/hip_bf16.h>
#include <math.h>

#define T_TOK 8192
#define NE 1024
#define N_EXP 8
#define DFFN 2048
#define TW 16384        // total width = 8*2048
#define P_TOT 16384     // T_TOK * 2

#define BM 256
#define BN 128
#define BKT 32

typedef __attribute__((ext_vector_type(8))) short bf16x8;
typedef __attribute__((ext_vector_type(4))) float f32x4;

#define GLOAD_LDS16(g, l) __builtin_amdgcn_global_load_lds( \
    (const __attribute__((address_space(1))) void*)(g), \
    (__attribute__((address_space(3))) void*)(l), 16, 0, 0)

static __device__ __forceinline__ unsigned short f2bf(float f) {
    __hip_bfloat16 b = __float2bfloat16(f);
    return *(unsigned short*)&b;
}

// ---------------------------------------------------------------------------
// Kernel A: router — logits, softmax, top-2, normalized weights, loss partials
// (f32 throughout: bf16 logits would flip near-tie top-k selections)
// ---------------------------------------------------------------------------
__global__ __launch_bounds__(256) void router_kernel(
    const float* __restrict__ x, const float* __restrict__ wr,
    int* __restrict__ sel_idx, float* __restrict__ sel_wt,
    float* __restrict__ z_part, float* __restrict__ p_part)
{
    __shared__ float wrs[N_EXP * NE];   // 32 KB
    __shared__ float red[256];
    int tid = threadIdx.x;
    for (int i = tid; i < N_EXP * NE; i += 256) wrs[i] = wr[i];
    __syncthreads();

    int t = blockIdx.x * 256 + tid;   // T_TOK == 32*256 exactly
    float lg[N_EXP];
#pragma unroll
    for (int e = 0; e < N_EXP; e++) lg[e] = 0.f;

    const float4* x4 = (const float4*)(x + (size_t)t * NE);
    for (int n4 = 0; n4 < NE / 4; n4++) {
        float4 xv = x4[n4];
#pragma unroll
        for (int e = 0; e < N_EXP; e++) {
            const float* w = &wrs[e * NE + n4 * 4];
            lg[e] += xv.x * w[0] + xv.y * w[1] + xv.z * w[2] + xv.w * w[3];
        }
    }

    float m = lg[0];
#pragma unroll
    for (int e = 1; e < N_EXP; e++) m = fmaxf(m, lg[e]);
    float p[N_EXP], s = 0.f;
#pragma unroll
    for (int e = 0; e < N_EXP; e++) { p[e] = expf(lg[e] - m); s += p[e]; }
    float inv = 1.f / s;
#pragma unroll
    for (int e = 0; e < N_EXP; e++) p[e] *= inv;
    float lse = m + logf(s);

    int e0 = 0;
#pragma unroll
    for (int e = 1; e < N_EXP; e++) if (p[e] > p[e0]) e0 = e;
    int e1 = (e0 == 0) ? 1 : 0;
#pragma unroll
    for (int e = 0; e < N_EXP; e++) if (e != e0 && p[e] > p[e1]) e1 = e;

    float wn = 1.f / (p[e0] + p[e1]);
    sel_idx[t * 2 + 0] = e0;
    sel_idx[t * 2 + 1] = e1;
    sel_wt[t * 2 + 0] = p[e0] * wn;
    sel_wt[t * 2 + 1] = p[e1] * wn;

    red[tid] = lse * lse;
    __syncthreads();
    for (int st = 128; st > 0; st >>= 1) {
        if (tid < st) red[tid] += red[tid + st];
        __syncthreads();
    }
    if (tid == 0) z_part[blockIdx.x] = red[0];
#pragma unroll
    for (int e = 0; e < N_EXP; e++) {
        __syncthreads();
        red[tid] = p[e];
        __syncthreads();
        for (int st = 128; st > 0; st >>= 1) {
            if (tid < st) red[tid] += red[tid + st];
            __syncthreads();
        }
        if (tid == 0) p_part[blockIdx.x * N_EXP + e] = red[0];
    }
}

// ---------------------------------------------------------------------------
// Kernel B: counts (by scan), offsets, cursors, tile table, aux-loss outputs
// ---------------------------------------------------------------------------
__global__ __launch_bounds__(256) void finalize_router(
    const int* __restrict__ sel_idx,
    const float* __restrict__ z_part, const float* __restrict__ p_part,
    int* __restrict__ cnt, int* __restrict__ off, int* __restrict__ cursor,
    int* __restrict__ tile_tab, int* __restrict__ tile_n,
    float* __restrict__ out)
{
    __shared__ int redc[256];
    __shared__ int cnts[N_EXP];
    int tid = threadIdx.x;
    int c[N_EXP];
#pragma unroll
    for (int e = 0; e < N_EXP; e++) c[e] = 0;
    for (int i = tid; i < P_TOT; i += 256) c[sel_idx[i]]++;
#pragma unroll
    for (int e = 0; e < N_EXP; e++) {
        redc[tid] = c[e];
        __syncthreads();
        for (int st = 128; st > 0; st >>= 1) {
            if (tid < st) redc[tid] += redc[tid + st];
            __syncthreads();
        }
        if (tid == 0) cnts[e] = redc[0];
        __syncthreads();
    }
    if (tid == 0) {
        int o = 0;
        int nt = 0;
        for (int e = 0; e < N_EXP; e++) {
            cnt[e] = cnts[e];
            off[e] = o;
            o += cnts[e];
            cursor[e] = 0;
            for (int rb = 0; rb < cnts[e]; rb += BM)
                tile_tab[nt++] = (e << 20) | rb;
        }
        off[N_EXP] = o;
        tile_n[0] = nt;
        float zs = 0.f;
        for (int b = 0; b < 32; b++) zs += z_part[b];
        float lb = 0.f;
        float* tail = out + (size_t)T_TOK * NE;
        for (int e = 0; e < N_EXP; e++) {
            float ps = 0.f;
            for (int b = 0; b < 32; b++) ps += p_part[b * N_EXP + e];
            float fi = (float)cnts[e] / (float)P_TOT;
            float pi = ps / (float)T_TOK;
            lb += fi * pi;
            tail[2 + e] = fi;
        }
        tail[0] = zs / (float)T_TOK;       // router_z_loss
        tail[1] = 8.f * lb;                // load_balance_loss
    }
}

// ---------------------------------------------------------------------------
// Kernel C: scatter (token,slot) pairs into per-expert lists
// ---------------------------------------------------------------------------
__global__ __launch_bounds__(256) void scatter_kernel(
    const int* __restrict__ sel_idx, const int* __restrict__ off,
    int* __restrict__ cursor, int* __restrict__ token_list)
{
    int i = blockIdx.x * 256 + threadIdx.x;
    if (i < P_TOT) {
        int e = sel_idx[i];
        int pos = atomicAdd(&cursor[e], 1);
        token_list[off[e] + pos] = i;   // token = i>>1, slot = i&1
    }
}

// ---------------------------------------------------------------------------
// Kernel P1: x f32 -> bf16 (same layout)
// ---------------------------------------------------------------------------
__global__ __launch_bounds__(256) void cvt_x_kernel(
    const float* __restrict__ x, unsigned short* __restrict__ xb)
{
    int i = blockIdx.x * 256 + threadIdx.x;     // one float4 per thread
    float4 v = ((const float4*)x)[i];
    ushort4 o;
    o.x = f2bf(v.x); o.y = f2bf(v.y); o.z = f2bf(v.z); o.w = f2bf(v.w);
    ((ushort4*)xb)[i] = o;
}

// ---------------------------------------------------------------------------
// Kernel P2: transpose + convert: src [R][C] f32 -> dst [C][R] bf16
// ---------------------------------------------------------------------------
__global__ __launch_bounds__(256) void transpose_bf16_kernel(
    const float* __restrict__ src, unsigned short* __restrict__ dst,
    int R, int C)
{
    __shared__ float tile[64][65];
    int rb = blockIdx.y * 64, cb = blockIdx.x * 64;
    int tid = threadIdx.x;
#pragma unroll
    for (int p = 0; p < 16; p++) {
        int idx = p * 256 + tid;
        int r = idx >> 6, c = idx & 63;
        tile[r][c] = src[(size_t)(rb + r) * C + cb + c];
    }
    __syncthreads();
#pragma unroll
    for (int p = 0; p < 16; p++) {
        int idx = p * 256 + tid;
        int c = idx >> 6, r = idx & 63;
        dst[(size_t)(cb + c) * R + rb + r] = f2bf(tile[r][c]);
    }
}

// ---------------------------------------------------------------------------
// Kernel D: grouped GEMM1, 256x128 tile, BK=32, 8 waves, double-buffered
// min-2-phase: stage(next) -> compute(cur) -> one barrier (vmcnt(0) drain).
// h[p,:] = selw[p] * gelu(xb[tok(p),:] @ W1_e)
// ---------------------------------------------------------------------------
__global__ __launch_bounds__(512) void gemm1_mfma(
    const __hip_bfloat16* __restrict__ xb, const __hip_bfloat16* __restrict__ w1t,
    const int* __restrict__ token_list, const float* __restrict__ sel_wt,
    const int* __restrict__ cnt, const int* __restrict__ off,
    const int* __restrict__ tile_tab, const int* __restrict__ tile_n,
    __hip_bfloat16* __restrict__ h)
{
    int flat = blockIdx.x;
    if (flat >= tile_n[0]) return;
    int tab = tile_tab[flat];
    int e = tab >> 20, rowbase = tab & 0xFFFFF;
    int off_e = off[e];
    int rows_e = cnt[e] - rowbase;
    int colbase = blockIdx.y * BN;

    __shared__ __hip_bfloat16 As[2][BM * BKT];   // 2 x 16 KB
    __shared__ __hip_bfloat16 Bs[2][BN * BKT];   // 2 x 8 KB

    int tid = threadIdx.x;
    int wid = tid >> 6, lane = tid & 63;
    int wm = wid >> 2, wn = wid & 3;

    // staging sources: A rows ra0/ra1, B col cbcol; each lane loads 16B at kcol
    int kcol = (lane & 3) * 8;
    int ra0 = wid * 16 + (lane >> 2);          // 0..127
    int ra1 = 128 + ra0;                       // 128..255
    int t0 = token_list[off_e + rowbase + ((ra0 < rows_e) ? ra0 : 0)];
    int t1 = token_list[off_e + rowbase + ((ra1 < rows_e) ? ra1 : 0)];
    const __hip_bfloat16* asrc0 = xb + (size_t)(t0 >> 1) * NE + kcol;
    const __hip_bfloat16* asrc1 = xb + (size_t)(t1 >> 1) * NE + kcol;
    int cbcol = colbase + wid * 16 + (lane >> 2);
    const __hip_bfloat16* bsrc = w1t + (size_t)(e * DFFN + cbcol) * NE + kcol;

    f32x4 acc[8][2] = {};
    int rr = lane & 15, kq = lane >> 4;

    GLOAD_LDS16(asrc0, &As[0][wid * 512]);
    GLOAD_LDS16(asrc1, &As[0][4096 + wid * 512]);
    GLOAD_LDS16(bsrc,  &Bs[0][wid * 512]);
    __syncthreads();

    for (int t = 0; t < NE / BKT; t++) {
        int cur = t & 1;
        if (t + 1 < NE / BKT) {
            int kb = (t + 1) * BKT;
            GLOAD_LDS16(asrc0 + kb, &As[cur ^ 1][wid * 512]);
            GLOAD_LDS16(asrc1 + kb, &As[cur ^ 1][4096 + wid * 512]);
            GLOAD_LDS16(bsrc  + kb, &Bs[cur ^ 1][wid * 512]);
        }
        bf16x8 af[8], bfr[2];
#pragma unroll
        for (int m = 0; m < 8; m++)
            af[m] = *(const bf16x8*)&As[cur][(wm * 128 + m * 16 + rr) * BKT + kq * 8];
#pragma unroll
        for (int n = 0; n < 2; n++)
            bfr[n] = *(const bf16x8*)&Bs[cur][(wn * 32 + n * 16 + rr) * BKT + kq * 8];
#pragma unroll
        for (int m = 0; m < 8; m++)
#pragma unroll
            for (int n = 0; n < 2; n++)
                acc[m][n] = __builtin_amdgcn_mfma_f32_16x16x32_bf16(
                    af[m], bfr[n], acc[m][n], 0, 0, 0);
        __syncthreads();   // drains vmcnt(0): next tile staged & ready
    }

    int colg = colbase + wn * 32;
#pragma unroll
    for (int m = 0; m < 8; m++) {
        int rb4 = wm * 128 + m * 16 + kq * 4;
#pragma unroll
        for (int j = 0; j < 4; j++) {
            int r = rb4 + j;
            if (r < rows_e) {
                size_t p = (size_t)off_e + rowbase + r;
                float wgt = sel_wt[token_list[p]];
#pragma unroll
                for (int n = 0; n < 2; n++) {
                    float v = acc[m][n][j];
                    float g = 0.5f * v * (1.f + erff(v * 0.70710678118f));
                    h[p * DFFN + colg + n * 16 + rr] = __float2bfloat16(wgt * g);
                }
            }
        }
    }
}

// ---------------------------------------------------------------------------
// Kernel E: grouped GEMM2, same structure, split-K=2 (blockIdx.z), atomic out.
// out[tok(p),:] += h[p,:] @ W2_e
// ---------------------------------------------------------------------------
__global__ __launch_bounds__(512) void gemm2_mfma(
    const __hip_bfloat16* __restrict__ h, const __hip_bfloat16* __restrict__ w2t,
    const int* __restrict__ token_list,
    const int* __restrict__ cnt, const int* __restrict__ off,
    const int* __restrict__ tile_tab, const int* __restrict__ tile_n,
    float* __restrict__ out)
{
    int flat = blockIdx.x;
    if (flat >= tile_n[0]) return;
    int tab = tile_tab[flat];
    int e = tab >> 20, rowbase = tab & 0xFFFFF;
    int off_e = off[e];
    int rows_e = cnt[e] - rowbase;
    int colbase = blockIdx.y * BN;
    int k0 = blockIdx.z * (DFFN / 2);          // split-K offset

    __shared__ __hip_bfloat16 As[2][BM * BKT];
    __shared__ __hip_bfloat16 Bs[2][BN * BKT];

    int tid = threadIdx.x;
    int wid = tid >> 6, lane = tid & 63;
    int wm = wid >> 2, wn = wid & 3;

    int kcol = (lane & 3) * 8;
    int ra0 = wid * 16 + (lane >> 2);
    int ra1 = 128 + ra0;
    int pr0 = off_e + rowbase + ((ra0 < rows_e) ? ra0 : 0);
    int pr1 = off_e + rowbase + ((ra1 < rows_e) ? ra1 : 0);
    const __hip_bfloat16* asrc0 = h + (size_t)pr0 * DFFN + k0 + kcol;
    const __hip_bfloat16* asrc1 = h + (size_t)pr1 * DFFN + k0 + kcol;
    int cbcol = colbase + wid * 16 + (lane >> 2);
    const __hip_bfloat16* bsrc = w2t + (size_t)cbcol * TW + e * DFFN + k0 + kcol;

    f32x4 acc[8][2] = {};
    int rr = lane & 15, kq = lane >> 4;

    GLOAD_LDS16(asrc0, &As[0][wid * 512]);
    GLOAD_LDS16(asrc1, &As[0][4096 + wid * 512]);
    GLOAD_LDS16(bsrc,  &Bs[0][wid * 512]);
    __syncthreads();

    const int NKT = (DFFN / 2) / BKT;   // 32
    for (int t = 0; t < NKT; t++) {
        int cur = t & 1;
        if (t + 1 < NKT) {
            int kb = (t + 1) * BKT;
            GLOAD_LDS16(asrc0 + kb, &As[cur ^ 1][wid * 512]);
            GLOAD_LDS16(asrc1 + kb, &As[cur ^ 1][4096 + wid * 512]);
            GLOAD_LDS16(bsrc  + kb, &Bs[cur ^ 1][wid * 512]);
        }
        bf16x8 af[8], bfr[2];
#pragma unroll
        for (int m = 0; m < 8; m++)
            af[m] = *(const bf16x8*)&As[cur][(wm * 128 + m * 16 + rr) * BKT + kq * 8];
#pragma unroll
        for (int n = 0; n < 2; n++)
            bfr[n] = *(const bf16x8*)&Bs[cur][(wn * 32 + n * 16 + rr) * BKT + kq * 8];
#pragma unroll
        for (int m = 0; m < 8; m++)
#pragma unroll
            for (int n = 0; n < 2; n++)
                acc[m][n] = __builtin_amdgcn_mfma_f32_16x16x32_bf16(
                    af[m], bfr[n], acc[m][n], 0, 0, 0);
        __syncthreads();
    }

    int colg = colbase + wn * 32;
#pragma unroll
    for (int m = 0; m < 8; m++) {
        int rb4 = wm * 128 + m * 16 + kq * 4;
#pragma unroll
        for (int j = 0; j < 4; j++) {
            int r = rb4 + j;
            if (r < rows_e) {
                size_t p = (size_t)off_e + rowbase + r;
                int tok = token_list[p] >> 1;
#pragma unroll
                for (int n = 0; n < 2; n++)
                    atomicAdd(&out[(size_t)tok * NE + colg + n * 16 + rr],
                              acc[m][n][j]);
            }
        }
    }
}

// ---------------------------------------------------------------------------
extern "C" void kernel_launch(void* const* d_in, const int* in_sizes, int n_in,
                              void* d_out, int out_size, void* d_ws, size_t ws_size,
                              hipStream_t stream)
{
    const float* x  = (const float*)d_in[0];
    const float* wr = (const float*)d_in[1];
    const float* w1 = (const float*)d_in[2];
    const float* w2 = (const float*)d_in[3];
    float* out = (float*)d_out;

    // workspace layout (~151.3 MB)
    char* ws = (char*)d_ws;
    size_t o = 0;
    __hip_bfloat16* h   = (__hip_bfloat16*)(ws + o); o += (size_t)P_TOT * DFFN * 2;  // 67.1MB
    __hip_bfloat16* xb  = (__hip_bfloat16*)(ws + o); o += (size_t)T_TOK * NE * 2;    // 16.8MB
    __hip_bfloat16* w1t = (__hip_bfloat16*)(ws + o); o += (size_t)NE * TW * 2;       // 33.6MB  [TW][NE]
    __hip_bfloat16* w2t = (__hip_bfloat16*)(ws + o); o += (size_t)TW * NE * 2;       // 33.6MB  [NE][TW]
    int*   sel_idx    = (int*)(ws + o);   o += P_TOT * 4;
    float* sel_wt     = (float*)(ws + o); o += P_TOT * 4;
    int*   token_list = (int*)(ws + o);   o += P_TOT * 4;
    int*   cnt        = (int*)(ws + o);   o += 64;
    int*   off        = (int*)(ws + o);   o += 64;
    int*   cursor     = (int*)(ws + o);   o += 64;
    int*   tile_tab   = (int*)(ws + o);   o += 128 * 4;
    int*   tile_n     = (int*)(ws + o);   o += 64;
    float* z_part     = (float*)(ws + o); o += 32 * 4;
    float* p_part     = (float*)(ws + o); o += 32 * N_EXP * 4;

    hipMemsetAsync(d_out, 0, (size_t)out_size * sizeof(float), stream);

    cvt_x_kernel<<<T_TOK * NE / 4 / 256, 256, 0, stream>>>(x, (unsigned short*)xb);
    transpose_bf16_kernel<<<dim3(TW / 64, NE / 64), 256, 0, stream>>>(
        w1, (unsigned short*)w1t, NE, TW);     // w1 [NE][TW] -> w1t [TW][NE]
    transpose_bf16_kernel<<<dim3(NE / 64, TW / 64), 256, 0, stream>>>(
        w2, (unsigned short*)w2t, TW, NE);     // w2 [TW][NE] -> w2t [NE][TW]

    router_kernel<<<32, 256, 0, stream>>>(x, wr, sel_idx, sel_wt, z_part, p_part);
    finalize_router<<<1, 256, 0, stream>>>(sel_idx, z_part, p_part, cnt, off, cursor,
                                           tile_tab, tile_n, out);
    scatter_kernel<<<64, 256, 0, stream>>>(sel_idx, off, cursor, token_list);

    // worst-case tiles: sum_e ceil(cnt_e/256) <= 64 + 7 = 71 -> grid.x = 72
    gemm1_mfma<<<dim3(72, DFFN / BN), 512, 0, stream>>>(
        xb, w1t, token_list, sel_wt, cnt, off, tile_tab, tile_n, h);
    gemm2_mfma<<<dim3(72, NE / BN, 2), 512, 0, stream>>>(
        h, w2t, token_list, cnt, off, tile_tab, tile_n, out);
}